// Round 14
// baseline (171.331 us; speedup 1.0000x reference)
//
#include <hip/hip_runtime.h>
#include <math.h>

#define N_TOT 8192
#define D 128
#define NIB (N_TOT / 128)               // 64 row-blocks
#define NPAIR (NIB * (NIB + 1) / 2)     // 2080 triangular tile-pairs
#define NBLK 512                        // exactly 2 blocks/CU resident (64KB LDS)
#define XTRA (NPAIR - NBLK * 4)         // 32 blocks carry a 5th pair

typedef unsigned short ushortT;
typedef __attribute__((ext_vector_type(8))) short short8;
typedef __attribute__((ext_vector_type(4))) float f32x4;

// ---------------- bf16 RNE ----------------
__device__ __forceinline__ ushortT f2bf(float f) {
    unsigned u = __float_as_uint(f);
    unsigned r = (u + 0x7FFF + ((u >> 16) & 1)) >> 16;   // RNE
    return (ushortT)r;
}

__device__ __forceinline__ float ld_agent_f32(const float* p) {
    return __hip_atomic_load(p, __ATOMIC_RELAXED, __HIP_MEMORY_SCOPE_AGENT);
}

// ---- prep: normalize rows + pack pos + zero E/S/C accumulators + done counter ----
__global__ __launch_bounds__(256) void prep_kernel(const float* __restrict__ h,
                                                   const float* __restrict__ pos,
                                                   unsigned* __restrict__ hn2,
                                                   float4* __restrict__ p4,
                                                   float* __restrict__ Earr,
                                                   float* __restrict__ Sarr,
                                                   float* __restrict__ Carr,
                                                   unsigned* __restrict__ tailw) {
    const int tid = threadIdx.x;
    const int wave = tid >> 6, lane = tid & 63;
    const int row = blockIdx.x * 4 + wave;
    float2 x = reinterpret_cast<const float2*>(h + (size_t)row * D)[lane];
    float ss = x.x * x.x + x.y * x.y;
#pragma unroll
    for (int m = 1; m < 64; m <<= 1) ss += __shfl_xor(ss, m, 64);
    float sc = 1.0f / fmaxf(sqrtf(ss), 1e-12f);
    unsigned lo = f2bf(x.x * sc), hi = f2bf(x.y * sc);
    hn2[(size_t)row * 64 + lane] = lo | (hi << 16);

    if (tid < 4) {
        int t = blockIdx.x * 4 + tid;
        float px = pos[3 * t], py = pos[3 * t + 1], pz = pos[3 * t + 2];
        p4[t] = make_float4(px, py, pz, px * px + py * py + pz * pz);
    }
    int g = blockIdx.x * 256 + tid;
    if (g < N_TOT) { Earr[g] = 0.f; Sarr[g] = 0.f; Carr[g] = 0.f; }   // atomic targets
    if (blockIdx.x == 0 && tid == 255) tailw[0] = 0u;                  // done counter
}

// ---------------- stage a 128x128 bf16 tile via global_load_lds, XOR-swizzled ----
// LDS dest is linear (gload_lds requirement); swizzle applied by permuting the
// GLOBAL source 16B-group: src col group = (lane&15) ^ (row&7). Readers apply
// the same XOR.  (both-sides-or-neither)
__device__ __forceinline__ void stage128_swz(const ushortT* __restrict__ src, ushortT* dst,
                                             int wave, int lane) {
#pragma unroll
    for (int it = 0; it < 8; ++it) {
        int c = it * 4 + wave;                  // 1 KB chunk = 4 rows
        int row = c * 4 + (lane >> 4);
        int g = (lane & 15) ^ (row & 7);        // pre-swizzled source col group
        const ushortT* gp = src + (size_t)row * D + g * 8;
        __builtin_amdgcn_global_load_lds(
            (const __attribute__((address_space(1))) unsigned int*)gp,
            (__attribute__((address_space(3))) unsigned int*)(dst + c * 512),
            16, 0, 0);
    }
}

// ---------------- A fragments straight from global (L2-hot) ----------------
__device__ __forceinline__ void loadA(const ushortT* __restrict__ hn, int ibase,
                                      int wave, int quad, int l15, short8 (&afr)[4][2]) {
#pragma unroll
    for (int ks = 0; ks < 4; ++ks)
#pragma unroll
        for (int r = 0; r < 2; ++r)
            afr[ks][r] = *reinterpret_cast<const short8*>(
                hn + (size_t)(ibase + wave * 32 + r * 16 + l15) * D + ks * 32 + quad * 8);
}

// ---------------- MFMA for one half-tile (4 c-columns) ----------------
__device__ __forceinline__ void mfma_half(const ushortT* __restrict__ Bs,
                                          const short8 (&afr)[4][2], int ch0,
                                          int quad, int l15, f32x4 (&acc)[2][4]) {
#pragma unroll
    for (int r = 0; r < 2; ++r)
#pragma unroll
        for (int cc = 0; cc < 4; ++cc) acc[r][cc] = (f32x4){0.f, 0.f, 0.f, 0.f};
#pragma unroll
    for (int ks = 0; ks < 4; ++ks) {
        short8 b[4];
#pragma unroll
        for (int cc = 0; cc < 4; ++cc)
            b[cc] = *reinterpret_cast<const short8*>(
                &Bs[((ch0 + cc) * 16 + l15) * D + (((ks * 4 + quad) ^ (l15 & 7)) * 8)]);
#pragma unroll
        for (int r = 0; r < 2; ++r)
#pragma unroll
            for (int cc = 0; cc < 4; ++cc)
                acc[r][cc] = __builtin_amdgcn_mfma_f32_16x16x32_bf16(
                    afr[ks][r], b[cc], acc[r][cc], 0, 0, 0);
    }
}

// ---------------- epilogue for one half-tile: row accum + col-side scatter ----
template<bool DIAG>
__device__ __forceinline__ void epi_half(const f32x4 (&acc)[2][4], int ch0,
                                         int ibase, int jbase,
                                         int wave, int quad, int l15,
                                         const float4* __restrict__ p4,
                                         float (&rowE)[8], float (&rowS)[8], float (&rowC)[8],
                                         float* __restrict__ Earr,
                                         float* __restrict__ Sarr,
                                         float* __restrict__ Carr) {
    float4 pj[4];
#pragma unroll
    for (int cc = 0; cc < 4; ++cc) pj[cc] = p4[jbase + (ch0 + cc) * 16 + l15];

    float cE[4], cS[4], cC[4];
#pragma unroll
    for (int cc = 0; cc < 4; ++cc) { cE[cc] = 0.f; cS[cc] = 0.f; cC[cc] = 0.f; }

#pragma unroll
    for (int idx = 0; idx < 8; ++idx) {
        const int r = idx >> 2, v = idx & 3;
        const int irow = wave * 32 + r * 16 + quad * 4 + v;
        float4 pi = p4[ibase + irow];               // uniform across l15 -> broadcast
        float wi = fmaf(-0.5f, pi.w, 0.125f);       // 0.125 - 0.5*|pi|^2
#pragma unroll
        for (int cc = 0; cc < 4; ++cc) {
            float s = acc[r][cc][v];                        // cosine sim (bf16 inputs)
            // exp(10s-10) = exp2((10*log2e)*s - 10*log2e): one v_exp, no extra mul
            float e = exp2f(fmaf(s, 14.4269504089f, -14.4269504089f));
            float t = fmaf(-0.5f, pj[cc].w, wi);            // 0.125 - 0.5(|pi|^2+|pj|^2)
            t = fmaf(pi.z, pj[cc].z, t);
            t = fmaf(pi.y, pj[cc].y, t);
            t = fmaf(pi.x, pj[cc].x, t);                    // t>0  <=>  d^2 < 0.25
            float m = (t > 0.f) ? 1.f : 0.f;
            if (DIAG) {
                bool self = (irow == (ch0 + cc) * 16 + l15);
                if (self) { e = 0.f; m = 0.f; }
            }
            rowE[idx] += e;
            rowC[idx] += m;
            rowS[idx] = fmaf(m, s, rowS[idx]);
            if (!DIAG) {                                    // col side (j-anchors)
                cE[cc] += e;
                cC[cc] += m;
                cS[cc] = fmaf(m, s, cS[cc]);
            }
        }
    }

    if (!DIAG) {
        // reduce col partials across the 4 quads (lane bits 4,5), then scatter;
        // 4 waves add independently via atomics
#pragma unroll
        for (int cc = 0; cc < 4; ++cc) {
#pragma unroll
            for (int msk = 16; msk < 64; msk <<= 1) {
                cE[cc] += __shfl_xor(cE[cc], msk, 64);
                cS[cc] += __shfl_xor(cS[cc], msk, 64);
                cC[cc] += __shfl_xor(cC[cc], msk, 64);
            }
        }
        if (quad == 0) {
#pragma unroll
            for (int cc = 0; cc < 4; ++cc) {
                int j = jbase + (ch0 + cc) * 16 + l15;
                atomicAdd(&Earr[j], cE[cc]);
                atomicAdd(&Sarr[j], cS[cc]);
                atomicAdd(&Carr[j], cC[cc]);
            }
        }
    }
}

// ---------------- flush row accumulators for the current I-block ----------------
__device__ __forceinline__ void flush_rows(int ibase, int wave, int quad, int l15,
                                           float (&rowE)[8], float (&rowS)[8], float (&rowC)[8],
                                           float* __restrict__ Earr,
                                           float* __restrict__ Sarr,
                                           float* __restrict__ Carr) {
#pragma unroll
    for (int idx = 0; idx < 8; ++idx) {
#pragma unroll
        for (int m = 1; m < 16; m <<= 1) {
            rowE[idx] += __shfl_xor(rowE[idx], m, 64);
            rowS[idx] += __shfl_xor(rowS[idx], m, 64);
            rowC[idx] += __shfl_xor(rowC[idx], m, 64);
        }
    }
    if (l15 == 0) {
#pragma unroll
        for (int idx = 0; idx < 8; ++idx) {
            int i = ibase + wave * 32 + (idx >> 2) * 16 + quad * 4 + (idx & 3);
            atomicAdd(&Earr[i], rowE[idx]);
            atomicAdd(&Sarr[i], rowS[idx]);
            atomicAdd(&Carr[i], rowC[idx]);
        }
    }
#pragma unroll
    for (int idx = 0; idx < 8; ++idx) { rowE[idx] = 0.f; rowS[idx] = 0.f; rowC[idx] = 0.f; }
}

// ---------------- triangular decode: g -> (I,J), J<=I ----------------
__device__ __forceinline__ void decodeIJ(int g, int& I, int& J) {
    int i = (int)((sqrtf(8.f * (float)g + 1.f) - 1.f) * 0.5f);
    while ((i + 1) * (i + 2) / 2 <= g) ++i;
    while (i * (i + 1) / 2 > g) --i;
    I = i; J = g - i * (i + 1) / 2;
}

// ---------------- round-6 body, CNT consecutive pairs, statically unrolled -------
template<int CNT>
__device__ __forceinline__ void run_pairs(int g0, const ushortT* __restrict__ hn,
                                          const float4* __restrict__ p4,
                                          float* __restrict__ Earr,
                                          float* __restrict__ Sarr,
                                          float* __restrict__ Carr,
                                          ushortT (&Bs)[2][128 * D],
                                          int wave, int lane, int quad, int l15) {
    int Iarr[CNT], Jarr[CNT];
    {
        int I, J;
        decodeIJ(g0, I, J);
#pragma unroll
        for (int p = 0; p < CNT; ++p) {
            Iarr[p] = I; Jarr[p] = J;
            if (++J > I) { ++I; J = 0; }
        }
    }

    stage128_swz(hn + (size_t)Jarr[0] * 128 * D, Bs[0], wave, lane);
    stage128_swz(hn + (size_t)Jarr[1] * 128 * D, Bs[1], wave, lane);

    short8 afr[4][2];
    loadA(hn, Iarr[0] * 128, wave, quad, l15, afr);

    float rowE[8], rowS[8], rowC[8];
#pragma unroll
    for (int idx = 0; idx < 8; ++idx) { rowE[idx] = 0.f; rowS[idx] = 0.f; rowC[idx] = 0.f; }

    __syncthreads();   // drains Bs[0]+Bs[1] staging (+afr loads)

#pragma unroll
    for (int p = 0; p < CNT; ++p) {
        const int ib = Iarr[p] * 128, jb = Jarr[p] * 128;
        const bool diag = (Iarr[p] == Jarr[p]);
        if (p && Iarr[p] != Iarr[p - 1]) {       // block-uniform, rare
            flush_rows(Iarr[p - 1] * 128, wave, quad, l15, rowE, rowS, rowC, Earr, Sarr, Carr);
            loadA(hn, ib, wave, quad, l15, afr);
        }
        const ushortT* Bcur = Bs[p & 1];

        f32x4 acc[2][4];
        mfma_half(Bcur, afr, 0, quad, l15, acc);
        if (diag) epi_half<true >(acc, 0, ib, jb, wave, quad, l15, p4, rowE, rowS, rowC, Earr, Sarr, Carr);
        else      epi_half<false>(acc, 0, ib, jb, wave, quad, l15, p4, rowE, rowS, rowC, Earr, Sarr, Carr);

        mfma_half(Bcur, afr, 4, quad, l15, acc);
        // all Bcur reads done; barrier also drains the in-flight staging of pair p+1
        __syncthreads();
        if (p + 2 < CNT)
            stage128_swz(hn + (size_t)Jarr[p + 2] * 128 * D, Bs[p & 1], wave, lane);

        if (diag) epi_half<true >(acc, 4, ib, jb, wave, quad, l15, p4, rowE, rowS, rowC, Earr, Sarr, Carr);
        else      epi_half<false>(acc, 4, ib, jb, wave, quad, l15, p4, rowE, rowS, rowC, Earr, Sarr, Carr);
    }

    flush_rows(Iarr[CNT - 1] * 128, wave, quad, l15, rowE, rowS, rowC, Earr, Sarr, Carr);
}

// ---------------- fused MFMA sim + softmax partials + last-block finalize --------
// Round-13 structure with the LDS cliff fixed: the isLast flag lives INSIDE Bs
// (dead after run_pairs) instead of a separate __shared__ int. r13's extra 4
// bytes made LDS 66048 > 65536 -> 1 block/CU -> 3x duration (r9 had the same
// 66048 cliff from its wqs[2]). Static LDS is now exactly 65536 -> 2 blocks/CU.
__global__ __launch_bounds__(256, 2) void main_kernel(const ushortT* __restrict__ hn,
                                                      const float4* __restrict__ p4,
                                                      float* __restrict__ Earr,
                                                      float* __restrict__ Sarr,
                                                      float* __restrict__ Carr,
                                                      unsigned* __restrict__ tailw,
                                                      float* __restrict__ out) {
    __shared__ ushortT Bs[2][128 * D];   // 64 KB double buffer; tail reuses as flag+scratch
    const int tid = threadIdx.x;
    const int wave = tid >> 6, lane = tid & 63;
    const int quad = lane >> 4, l15 = lane & 15;
    const int b = (int)blockIdx.x;

    if (b < XTRA)
        run_pairs<5>(b * 5, hn, p4, Earr, Sarr, Carr, Bs, wave, lane, quad, l15);
    else
        run_pairs<4>(XTRA * 5 + (b - XTRA) * 4, hn, p4, Earr, Sarr, Carr, Bs, wave, lane, quad, l15);

    // ---- last-block finalize (flag stored in Bs: LDS stays at exactly 64KB) ----
    int* iflag = reinterpret_cast<int*>(Bs);
    __threadfence();      // make this block's atomics visible device-wide
    __syncthreads();      // all waves' fences retired; Bs dead -> reusable
    if (tid == 0) {
        unsigned old = atomicAdd(tailw, 1u);
        iflag[0] = (old == NBLK - 1) ? 1 : 0;
    }
    __syncthreads();
    const int isLast = iflag[0];   // block-uniform
    __syncthreads();               // everyone has read the flag before Bs reuse
    if (isLast) {
        __threadfence();  // acquire side
        float L = 0.f, V = 0.f;
        for (int a = tid; a < N_TOT; a += 256) {   // 32 anchors/thread, fixed order
            float E = ld_agent_f32(&Earr[a]);
            float S = ld_agent_f32(&Sarr[a]);
            float C = ld_agent_f32(&Carr[a]);
            if (C > 0.f) {
                float lse = 10.0f + logf(E);
                L += -(10.0f * S - C * lse) / C;   // S stored in sim units
                V += 1.0f;
            }
        }
#pragma unroll
        for (int m = 1; m < 64; m <<= 1) {
            L += __shfl_xor(L, m, 64);
            V += __shfl_xor(V, m, 64);
        }
        float* sf = reinterpret_cast<float*>(Bs);  // LDS reuse (post-flag, barrier'd)
        if (lane == 0) { sf[wave] = L; sf[4 + wave] = V; }
        __syncthreads();
        if (tid == 0) {
            float Lv = sf[0] + sf[1] + sf[2] + sf[3];   // fixed order: deterministic
            float Vv = sf[4] + sf[5] + sf[6] + sf[7];
            out[0] = Lv / fmaxf(Vv, 1.0f);
        }
    }
}

extern "C" void kernel_launch(void* const* d_in, const int* in_sizes, int n_in,
                              void* d_out, int out_size, void* d_ws, size_t ws_size,
                              hipStream_t stream) {
    const float* h = (const float*)d_in[0];     // [8,1024,128] fp32
    const float* pos = (const float*)d_in[1];   // [8,1024,3] fp32
    float* out = (float*)d_out;                 // scalar fp32

    char* ws = (char*)d_ws;
    ushortT* hn = (ushortT*)ws;                                   // 8192*128*2 = 2 MB bf16
    float4* p4 = (float4*)(ws + (size_t)N_TOT * D * 2);           // 128 KB
    char* p = ws + (size_t)N_TOT * D * 2 + (size_t)N_TOT * 16;
    float* Earr = (float*)p; p += (size_t)N_TOT * 4;              // 32 KB
    float* Sarr = (float*)p; p += (size_t)N_TOT * 4;              // 32 KB
    float* Carr = (float*)p; p += (size_t)N_TOT * 4;              // 32 KB
    unsigned* tailw = (unsigned*)p;                               // done counter

    prep_kernel<<<N_TOT / 4, 256, 0, stream>>>(h, pos, (unsigned*)hn, p4,
                                               Earr, Sarr, Carr, tailw);
    main_kernel<<<NBLK, 256, 0, stream>>>(hn, p4, Earr, Sarr, Carr, tailw, out);
}

// Round 16
// 150.959 us; speedup vs baseline: 1.1350x; 1.1350x over previous
//
#include <hip/hip_runtime.h>
#include <math.h>

#define N_TOT 8192
#define D 128
#define NIB (N_TOT / 128)               // 64 row-blocks
#define NPAIR (NIB * (NIB + 1) / 2)     // 2080 triangular tile-pairs
#define NBLK 512                        // exactly 2 blocks/CU resident (64KB LDS)
#define XTRA (NPAIR - NBLK * 4)         // 32 blocks carry a 5th pair

typedef unsigned short ushortT;
typedef __attribute__((ext_vector_type(8))) short short8;
typedef __attribute__((ext_vector_type(4))) float f32x4;

// ---------------- bf16 RNE ----------------
__device__ __forceinline__ ushortT f2bf(float f) {
    unsigned u = __float_as_uint(f);
    unsigned r = (u + 0x7FFF + ((u >> 16) & 1)) >> 16;   // RNE
    return (ushortT)r;
}

__device__ __forceinline__ float ld_agent_f32(const float* p) {
    return __hip_atomic_load(p, __ATOMIC_RELAXED, __HIP_MEMORY_SCOPE_AGENT);
}

// ---- prep: normalize rows + pack pos + zero E/S/C accumulators + done counter ----
__global__ __launch_bounds__(256) void prep_kernel(const float* __restrict__ h,
                                                   const float* __restrict__ pos,
                                                   unsigned* __restrict__ hn2,
                                                   float4* __restrict__ p4,
                                                   float* __restrict__ Earr,
                                                   float* __restrict__ Sarr,
                                                   float* __restrict__ Carr,
                                                   unsigned* __restrict__ tailw) {
    const int tid = threadIdx.x;
    const int wave = tid >> 6, lane = tid & 63;
    const int row = blockIdx.x * 4 + wave;
    float2 x = reinterpret_cast<const float2*>(h + (size_t)row * D)[lane];
    float ss = x.x * x.x + x.y * x.y;
#pragma unroll
    for (int m = 1; m < 64; m <<= 1) ss += __shfl_xor(ss, m, 64);
    float sc = 1.0f / fmaxf(sqrtf(ss), 1e-12f);
    unsigned lo = f2bf(x.x * sc), hi = f2bf(x.y * sc);
    hn2[(size_t)row * 64 + lane] = lo | (hi << 16);

    if (tid < 4) {
        int t = blockIdx.x * 4 + tid;
        float px = pos[3 * t], py = pos[3 * t + 1], pz = pos[3 * t + 2];
        p4[t] = make_float4(px, py, pz, px * px + py * py + pz * pz);
    }
    int g = blockIdx.x * 256 + tid;
    if (g < N_TOT) { Earr[g] = 0.f; Sarr[g] = 0.f; Carr[g] = 0.f; }   // atomic targets
    if (blockIdx.x == 0 && tid == 255) tailw[0] = 0u;                  // done counter
}

// ---------------- stage a 128x128 bf16 tile via global_load_lds, XOR-swizzled ----
// LDS dest is linear (gload_lds requirement); swizzle applied by permuting the
// GLOBAL source 16B-group: src col group = (lane&15) ^ (row&7). Readers apply
// the same XOR.  (both-sides-or-neither)
__device__ __forceinline__ void stage128_swz(const ushortT* __restrict__ src, ushortT* dst,
                                             int wave, int lane) {
#pragma unroll
    for (int it = 0; it < 8; ++it) {
        int c = it * 4 + wave;                  // 1 KB chunk = 4 rows
        int row = c * 4 + (lane >> 4);
        int g = (lane & 15) ^ (row & 7);        // pre-swizzled source col group
        const ushortT* gp = src + (size_t)row * D + g * 8;
        __builtin_amdgcn_global_load_lds(
            (const __attribute__((address_space(1))) unsigned int*)gp,
            (__attribute__((address_space(3))) unsigned int*)(dst + c * 512),
            16, 0, 0);
    }
}

// ---------------- A fragments straight from global (L2-hot) ----------------
__device__ __forceinline__ void loadA(const ushortT* __restrict__ hn, int ibase,
                                      int wave, int quad, int l15, short8 (&afr)[4][2]) {
#pragma unroll
    for (int ks = 0; ks < 4; ++ks)
#pragma unroll
        for (int r = 0; r < 2; ++r)
            afr[ks][r] = *reinterpret_cast<const short8*>(
                hn + (size_t)(ibase + wave * 32 + r * 16 + l15) * D + ks * 32 + quad * 8);
}

// ---------------- MFMA for one half-tile (4 c-columns) ----------------
__device__ __forceinline__ void mfma_half(const ushortT* __restrict__ Bs,
                                          const short8 (&afr)[4][2], int ch0,
                                          int quad, int l15, f32x4 (&acc)[2][4]) {
#pragma unroll
    for (int r = 0; r < 2; ++r)
#pragma unroll
        for (int cc = 0; cc < 4; ++cc) acc[r][cc] = (f32x4){0.f, 0.f, 0.f, 0.f};
#pragma unroll
    for (int ks = 0; ks < 4; ++ks) {
        short8 b[4];
#pragma unroll
        for (int cc = 0; cc < 4; ++cc)
            b[cc] = *reinterpret_cast<const short8*>(
                &Bs[((ch0 + cc) * 16 + l15) * D + (((ks * 4 + quad) ^ (l15 & 7)) * 8)]);
#pragma unroll
        for (int r = 0; r < 2; ++r)
#pragma unroll
            for (int cc = 0; cc < 4; ++cc)
                acc[r][cc] = __builtin_amdgcn_mfma_f32_16x16x32_bf16(
                    afr[ks][r], b[cc], acc[r][cc], 0, 0, 0);
    }
}

// ---------------- epilogue for one half-tile: row accum + col-side scatter ----
template<bool DIAG>
__device__ __forceinline__ void epi_half(const f32x4 (&acc)[2][4], int ch0,
                                         int ibase, int jbase,
                                         int wave, int quad, int l15,
                                         const float4* __restrict__ p4,
                                         float (&rowE)[8], float (&rowS)[8], float (&rowC)[8],
                                         float* __restrict__ Earr,
                                         float* __restrict__ Sarr,
                                         float* __restrict__ Carr) {
    float4 pj[4];
#pragma unroll
    for (int cc = 0; cc < 4; ++cc) pj[cc] = p4[jbase + (ch0 + cc) * 16 + l15];

    float cE[4], cS[4], cC[4];
#pragma unroll
    for (int cc = 0; cc < 4; ++cc) { cE[cc] = 0.f; cS[cc] = 0.f; cC[cc] = 0.f; }

#pragma unroll
    for (int idx = 0; idx < 8; ++idx) {
        const int r = idx >> 2, v = idx & 3;
        const int irow = wave * 32 + r * 16 + quad * 4 + v;
        float4 pi = p4[ibase + irow];               // uniform across l15 -> broadcast
        float wi = fmaf(-0.5f, pi.w, 0.125f);       // 0.125 - 0.5*|pi|^2
#pragma unroll
        for (int cc = 0; cc < 4; ++cc) {
            float s = acc[r][cc][v];                        // cosine sim (bf16 inputs)
            // exp(10s-10) = exp2((10*log2e)*s - 10*log2e): one v_exp, no extra mul
            float e = exp2f(fmaf(s, 14.4269504089f, -14.4269504089f));
            float t = fmaf(-0.5f, pj[cc].w, wi);            // 0.125 - 0.5(|pi|^2+|pj|^2)
            t = fmaf(pi.z, pj[cc].z, t);
            t = fmaf(pi.y, pj[cc].y, t);
            t = fmaf(pi.x, pj[cc].x, t);                    // t>0  <=>  d^2 < 0.25
            float m = (t > 0.f) ? 1.f : 0.f;
            if (DIAG) {
                bool self = (irow == (ch0 + cc) * 16 + l15);
                if (self) { e = 0.f; m = 0.f; }
            }
            rowE[idx] += e;
            rowC[idx] += m;
            rowS[idx] = fmaf(m, s, rowS[idx]);
            if (!DIAG) {                                    // col side (j-anchors)
                cE[cc] += e;
                cC[cc] += m;
                cS[cc] = fmaf(m, s, cS[cc]);
            }
        }
    }

    if (!DIAG) {
        // reduce col partials across the 4 quads (lane bits 4,5), then scatter;
        // 4 waves add independently via atomics
#pragma unroll
        for (int cc = 0; cc < 4; ++cc) {
#pragma unroll
            for (int msk = 16; msk < 64; msk <<= 1) {
                cE[cc] += __shfl_xor(cE[cc], msk, 64);
                cS[cc] += __shfl_xor(cS[cc], msk, 64);
                cC[cc] += __shfl_xor(cC[cc], msk, 64);
            }
        }
        if (quad == 0) {
#pragma unroll
            for (int cc = 0; cc < 4; ++cc) {
                int j = jbase + (ch0 + cc) * 16 + l15;
                atomicAdd(&Earr[j], cE[cc]);
                atomicAdd(&Sarr[j], cS[cc]);
                atomicAdd(&Carr[j], cC[cc]);
            }
        }
    }
}

// ---------------- flush row accumulators for the current I-block ----------------
__device__ __forceinline__ void flush_rows(int ibase, int wave, int quad, int l15,
                                           float (&rowE)[8], float (&rowS)[8], float (&rowC)[8],
                                           float* __restrict__ Earr,
                                           float* __restrict__ Sarr,
                                           float* __restrict__ Carr) {
#pragma unroll
    for (int idx = 0; idx < 8; ++idx) {
#pragma unroll
        for (int m = 1; m < 16; m <<= 1) {
            rowE[idx] += __shfl_xor(rowE[idx], m, 64);
            rowS[idx] += __shfl_xor(rowS[idx], m, 64);
            rowC[idx] += __shfl_xor(rowC[idx], m, 64);
        }
    }
    if (l15 == 0) {
#pragma unroll
        for (int idx = 0; idx < 8; ++idx) {
            int i = ibase + wave * 32 + (idx >> 2) * 16 + quad * 4 + (idx & 3);
            atomicAdd(&Earr[i], rowE[idx]);
            atomicAdd(&Sarr[i], rowS[idx]);
            atomicAdd(&Carr[i], rowC[idx]);
        }
    }
#pragma unroll
    for (int idx = 0; idx < 8; ++idx) { rowE[idx] = 0.f; rowS[idx] = 0.f; rowC[idx] = 0.f; }
}

// ---------------- triangular decode: g -> (I,J), J<=I ----------------
__device__ __forceinline__ void decodeIJ(int g, int& I, int& J) {
    int i = (int)((sqrtf(8.f * (float)g + 1.f) - 1.f) * 0.5f);
    while ((i + 1) * (i + 2) / 2 <= g) ++i;
    while (i * (i + 1) / 2 > g) --i;
    I = i; J = g - i * (i + 1) / 2;
}

// ---------------- round-6 body, CNT consecutive pairs, statically unrolled -------
template<int CNT>
__device__ __forceinline__ void run_pairs(int g0, const ushortT* __restrict__ hn,
                                          const float4* __restrict__ p4,
                                          float* __restrict__ Earr,
                                          float* __restrict__ Sarr,
                                          float* __restrict__ Carr,
                                          ushortT (&Bs)[2][128 * D],
                                          int wave, int lane, int quad, int l15) {
    int Iarr[CNT], Jarr[CNT];
    {
        int I, J;
        decodeIJ(g0, I, J);
#pragma unroll
        for (int p = 0; p < CNT; ++p) {
            Iarr[p] = I; Jarr[p] = J;
            if (++J > I) { ++I; J = 0; }
        }
    }

    stage128_swz(hn + (size_t)Jarr[0] * 128 * D, Bs[0], wave, lane);
    stage128_swz(hn + (size_t)Jarr[1] * 128 * D, Bs[1], wave, lane);

    short8 afr[4][2];
    loadA(hn, Iarr[0] * 128, wave, quad, l15, afr);

    float rowE[8], rowS[8], rowC[8];
#pragma unroll
    for (int idx = 0; idx < 8; ++idx) { rowE[idx] = 0.f; rowS[idx] = 0.f; rowC[idx] = 0.f; }

    __syncthreads();   // drains Bs[0]+Bs[1] staging (+afr loads)

#pragma unroll
    for (int p = 0; p < CNT; ++p) {
        const int ib = Iarr[p] * 128, jb = Jarr[p] * 128;
        const bool diag = (Iarr[p] == Jarr[p]);
        if (p && Iarr[p] != Iarr[p - 1]) {       // block-uniform, rare
            flush_rows(Iarr[p - 1] * 128, wave, quad, l15, rowE, rowS, rowC, Earr, Sarr, Carr);
            loadA(hn, ib, wave, quad, l15, afr);
        }
        const ushortT* Bcur = Bs[p & 1];

        f32x4 acc[2][4];
        mfma_half(Bcur, afr, 0, quad, l15, acc);
        if (diag) epi_half<true >(acc, 0, ib, jb, wave, quad, l15, p4, rowE, rowS, rowC, Earr, Sarr, Carr);
        else      epi_half<false>(acc, 0, ib, jb, wave, quad, l15, p4, rowE, rowS, rowC, Earr, Sarr, Carr);

        mfma_half(Bcur, afr, 4, quad, l15, acc);
        // all Bcur reads done; barrier also drains the in-flight staging of pair p+1
        __syncthreads();
        if (p + 2 < CNT)
            stage128_swz(hn + (size_t)Jarr[p + 2] * 128 * D, Bs[p & 1], wave, lane);

        if (diag) epi_half<true >(acc, 4, ib, jb, wave, quad, l15, p4, rowE, rowS, rowC, Earr, Sarr, Carr);
        else      epi_half<false>(acc, 4, ib, jb, wave, quad, l15, p4, rowE, rowS, rowC, Earr, Sarr, Carr);
    }

    flush_rows(Iarr[CNT - 1] * 128, wave, quad, l15, rowE, rowS, rowC, Earr, Sarr, Carr);
}

// ---------------- fused MFMA sim + softmax partials + last-block finalize --------
// Round-14 minus the two __threadfence() calls. Diagnosis: r13/r14 counters show
// the 43us loop intact (VALUBusy/MfmaUtil diluted exactly by 43/145) plus ~100us
// of idle tail. __threadfence emits buffer_wbl2 — an L2 TAG-WALK writeback, ~us
// each, serialized per-XCD over 64 finishing blocks. It's also unnecessary: all
// cross-block writes here are device-scope atomics at the coherent point (nothing
// dirty in L2), and __syncthreads already drains vmcnt(0) per wave, ordering each
// wave's atomics before tid0's counter bump. Reader side uses sc0/sc1 agent loads
// that bypass L1/L2.
__global__ __launch_bounds__(256, 2) void main_kernel(const ushortT* __restrict__ hn,
                                                      const float4* __restrict__ p4,
                                                      float* __restrict__ Earr,
                                                      float* __restrict__ Sarr,
                                                      float* __restrict__ Carr,
                                                      unsigned* __restrict__ tailw,
                                                      float* __restrict__ out) {
    __shared__ ushortT Bs[2][128 * D];   // 64 KB double buffer; tail reuses as flag+scratch
    const int tid = threadIdx.x;
    const int wave = tid >> 6, lane = tid & 63;
    const int quad = lane >> 4, l15 = lane & 15;
    const int b = (int)blockIdx.x;

    if (b < XTRA)
        run_pairs<5>(b * 5, hn, p4, Earr, Sarr, Carr, Bs, wave, lane, quad, l15);
    else
        run_pairs<4>(XTRA * 5 + (b - XTRA) * 4, hn, p4, Earr, Sarr, Carr, Bs, wave, lane, quad, l15);

    // ---- last-block finalize (no threadfence: see header comment) ----
    int* iflag = reinterpret_cast<int*>(Bs);
    asm volatile("s_waitcnt vmcnt(0)" ::: "memory");  // own atomics acked (free: barrier drains too)
    __syncthreads();      // all waves' atomics drained; Bs dead -> reusable
    if (tid == 0) {
        unsigned old = atomicAdd(tailw, 1u);
        iflag[0] = (old == NBLK - 1) ? 1 : 0;
    }
    __syncthreads();
    const int isLast = iflag[0];   // block-uniform
    __syncthreads();               // everyone has read the flag before Bs reuse
    if (isLast) {
        float L = 0.f, V = 0.f;
        for (int a = tid; a < N_TOT; a += 256) {   // 32 anchors/thread, fixed order
            float E = ld_agent_f32(&Earr[a]);      // sc0 sc1: reads coherent point
            float S = ld_agent_f32(&Sarr[a]);
            float C = ld_agent_f32(&Carr[a]);
            if (C > 0.f) {
                float lse = 10.0f + logf(E);
                L += -(10.0f * S - C * lse) / C;   // S stored in sim units
                V += 1.0f;
            }
        }
#pragma unroll
        for (int m = 1; m < 64; m <<= 1) {
            L += __shfl_xor(L, m, 64);
            V += __shfl_xor(V, m, 64);
        }
        float* sf = reinterpret_cast<float*>(Bs);  // LDS reuse (post-flag, barrier'd)
        if (lane == 0) { sf[wave] = L; sf[4 + wave] = V; }
        __syncthreads();
        if (tid == 0) {
            float Lv = sf[0] + sf[1] + sf[2] + sf[3];   // fixed order: deterministic
            float Vv = sf[4] + sf[5] + sf[6] + sf[7];
            out[0] = Lv / fmaxf(Vv, 1.0f);
        }
    }
}

extern "C" void kernel_launch(void* const* d_in, const int* in_sizes, int n_in,
                              void* d_out, int out_size, void* d_ws, size_t ws_size,
                              hipStream_t stream) {
    const float* h = (const float*)d_in[0];     // [8,1024,128] fp32
    const float* pos = (const float*)d_in[1];   // [8,1024,3] fp32
    float* out = (float*)d_out;                 // scalar fp32

    char* ws = (char*)d_ws;
    ushortT* hn = (ushortT*)ws;                                   // 8192*128*2 = 2 MB bf16
    float4* p4 = (float4*)(ws + (size_t)N_TOT * D * 2);           // 128 KB
    char* p = ws + (size_t)N_TOT * D * 2 + (size_t)N_TOT * 16;
    float* Earr = (float*)p; p += (size_t)N_TOT * 4;              // 32 KB
    float* Sarr = (float*)p; p += (size_t)N_TOT * 4;              // 32 KB
    float* Carr = (float*)p; p += (size_t)N_TOT * 4;              // 32 KB
    unsigned* tailw = (unsigned*)p;                               // done counter

    prep_kernel<<<N_TOT / 4, 256, 0, stream>>>(h, pos, (unsigned*)hn, p4,
                                               Earr, Sarr, Carr, tailw);
    main_kernel<<<NBLK, 256, 0, stream>>>(hn, p4, Earr, Sarr, Carr, tailw, out);
}

// Round 17
// 100.836 us; speedup vs baseline: 1.6991x; 1.4971x over previous
//
#include <hip/hip_runtime.h>
#include <math.h>

#define N_TOT 8192
#define D 128
#define NIB (N_TOT / 128)               // 64 row-blocks
#define NPAIR (NIB * (NIB + 1) / 2)     // 2080 triangular tile-pairs
#define NBLK 512                        // exactly 2 blocks/CU resident (64KB LDS)
#define XTRA (NPAIR - NBLK * 4)         // 32 blocks carry a 5th pair

typedef unsigned short ushortT;
typedef __attribute__((ext_vector_type(8))) short short8;
typedef __attribute__((ext_vector_type(4))) float f32x4;

// ---------------- bf16 RNE ----------------
__device__ __forceinline__ ushortT f2bf(float f) {
    unsigned u = __float_as_uint(f);
    unsigned r = (u + 0x7FFF + ((u >> 16) & 1)) >> 16;   // RNE
    return (ushortT)r;
}

// ---- prep: normalize rows + pack pos + zero E/S/C accumulators + tail counter ----
__global__ __launch_bounds__(256) void prep_kernel(const float* __restrict__ h,
                                                   const float* __restrict__ pos,
                                                   unsigned* __restrict__ hn2,
                                                   float4* __restrict__ p4,
                                                   float* __restrict__ Earr,
                                                   float* __restrict__ Sarr,
                                                   float* __restrict__ Carr,
                                                   unsigned* __restrict__ tailw) {
    const int tid = threadIdx.x;
    const int wave = tid >> 6, lane = tid & 63;
    const int row = blockIdx.x * 4 + wave;
    float2 x = reinterpret_cast<const float2*>(h + (size_t)row * D)[lane];
    float ss = x.x * x.x + x.y * x.y;
#pragma unroll
    for (int m = 1; m < 64; m <<= 1) ss += __shfl_xor(ss, m, 64);
    float sc = 1.0f / fmaxf(sqrtf(ss), 1e-12f);
    unsigned lo = f2bf(x.x * sc), hi = f2bf(x.y * sc);
    hn2[(size_t)row * 64 + lane] = lo | (hi << 16);

    if (tid < 4) {
        int t = blockIdx.x * 4 + tid;
        float px = pos[3 * t], py = pos[3 * t + 1], pz = pos[3 * t + 2];
        p4[t] = make_float4(px, py, pz, px * px + py * py + pz * pz);
    }
    int g = blockIdx.x * 256 + tid;
    if (g < N_TOT) { Earr[g] = 0.f; Sarr[g] = 0.f; Carr[g] = 0.f; }   // atomic targets
    if (blockIdx.x == 0 && tid == 255) tailw[0] = 0u;                  // finalize counter
}

// ---------------- stage a 128x128 bf16 tile via global_load_lds, XOR-swizzled ----
// LDS dest is linear (gload_lds requirement); swizzle applied by permuting the
// GLOBAL source 16B-group: src col group = (lane&15) ^ (row&7). Readers apply
// the same XOR.  (both-sides-or-neither)
__device__ __forceinline__ void stage128_swz(const ushortT* __restrict__ src, ushortT* dst,
                                             int wave, int lane) {
#pragma unroll
    for (int it = 0; it < 8; ++it) {
        int c = it * 4 + wave;                  // 1 KB chunk = 4 rows
        int row = c * 4 + (lane >> 4);
        int g = (lane & 15) ^ (row & 7);        // pre-swizzled source col group
        const ushortT* gp = src + (size_t)row * D + g * 8;
        __builtin_amdgcn_global_load_lds(
            (const __attribute__((address_space(1))) unsigned int*)gp,
            (__attribute__((address_space(3))) unsigned int*)(dst + c * 512),
            16, 0, 0);
    }
}

// ---------------- A fragments straight from global (L2-hot) ----------------
__device__ __forceinline__ void loadA(const ushortT* __restrict__ hn, int ibase,
                                      int wave, int quad, int l15, short8 (&afr)[4][2]) {
#pragma unroll
    for (int ks = 0; ks < 4; ++ks)
#pragma unroll
        for (int r = 0; r < 2; ++r)
            afr[ks][r] = *reinterpret_cast<const short8*>(
                hn + (size_t)(ibase + wave * 32 + r * 16 + l15) * D + ks * 32 + quad * 8);
}

// ---------------- MFMA for one half-tile (4 c-columns) ----------------
__device__ __forceinline__ void mfma_half(const ushortT* __restrict__ Bs,
                                          const short8 (&afr)[4][2], int ch0,
                                          int quad, int l15, f32x4 (&acc)[2][4]) {
#pragma unroll
    for (int r = 0; r < 2; ++r)
#pragma unroll
        for (int cc = 0; cc < 4; ++cc) acc[r][cc] = (f32x4){0.f, 0.f, 0.f, 0.f};
#pragma unroll
    for (int ks = 0; ks < 4; ++ks) {
        short8 b[4];
#pragma unroll
        for (int cc = 0; cc < 4; ++cc)
            b[cc] = *reinterpret_cast<const short8*>(
                &Bs[((ch0 + cc) * 16 + l15) * D + (((ks * 4 + quad) ^ (l15 & 7)) * 8)]);
#pragma unroll
        for (int r = 0; r < 2; ++r)
#pragma unroll
            for (int cc = 0; cc < 4; ++cc)
                acc[r][cc] = __builtin_amdgcn_mfma_f32_16x16x32_bf16(
                    afr[ks][r], b[cc], acc[r][cc], 0, 0, 0);
    }
}

// ---------------- epilogue for one half-tile: row accum + col-side scatter ----
template<bool DIAG>
__device__ __forceinline__ void epi_half(const f32x4 (&acc)[2][4], int ch0,
                                         int ibase, int jbase,
                                         int wave, int quad, int l15,
                                         const float4* __restrict__ p4,
                                         float (&rowE)[8], float (&rowS)[8], float (&rowC)[8],
                                         float* __restrict__ Earr,
                                         float* __restrict__ Sarr,
                                         float* __restrict__ Carr) {
    float4 pj[4];
#pragma unroll
    for (int cc = 0; cc < 4; ++cc) pj[cc] = p4[jbase + (ch0 + cc) * 16 + l15];

    float cE[4], cS[4], cC[4];
#pragma unroll
    for (int cc = 0; cc < 4; ++cc) { cE[cc] = 0.f; cS[cc] = 0.f; cC[cc] = 0.f; }

#pragma unroll
    for (int idx = 0; idx < 8; ++idx) {
        const int r = idx >> 2, v = idx & 3;
        const int irow = wave * 32 + r * 16 + quad * 4 + v;
        float4 pi = p4[ibase + irow];               // uniform across l15 -> broadcast
        float wi = fmaf(-0.5f, pi.w, 0.125f);       // 0.125 - 0.5*|pi|^2
#pragma unroll
        for (int cc = 0; cc < 4; ++cc) {
            float s = acc[r][cc][v];                        // cosine sim (bf16 inputs)
            // exp(10s-10) = exp2((10*log2e)*s - 10*log2e): one v_exp, no extra mul
            float e = exp2f(fmaf(s, 14.4269504089f, -14.4269504089f));
            float t = fmaf(-0.5f, pj[cc].w, wi);            // 0.125 - 0.5(|pi|^2+|pj|^2)
            t = fmaf(pi.z, pj[cc].z, t);
            t = fmaf(pi.y, pj[cc].y, t);
            t = fmaf(pi.x, pj[cc].x, t);                    // t>0  <=>  d^2 < 0.25
            float m = (t > 0.f) ? 1.f : 0.f;
            if (DIAG) {
                bool self = (irow == (ch0 + cc) * 16 + l15);
                if (self) { e = 0.f; m = 0.f; }
            }
            rowE[idx] += e;
            rowC[idx] += m;
            rowS[idx] = fmaf(m, s, rowS[idx]);
            if (!DIAG) {                                    // col side (j-anchors)
                cE[cc] += e;
                cC[cc] += m;
                cS[cc] = fmaf(m, s, cS[cc]);
            }
        }
    }

    if (!DIAG) {
        // reduce col partials across the 4 quads (lane bits 4,5), then scatter;
        // 4 waves add independently via atomics
#pragma unroll
        for (int cc = 0; cc < 4; ++cc) {
#pragma unroll
            for (int msk = 16; msk < 64; msk <<= 1) {
                cE[cc] += __shfl_xor(cE[cc], msk, 64);
                cS[cc] += __shfl_xor(cS[cc], msk, 64);
                cC[cc] += __shfl_xor(cC[cc], msk, 64);
            }
        }
        if (quad == 0) {
#pragma unroll
            for (int cc = 0; cc < 4; ++cc) {
                int j = jbase + (ch0 + cc) * 16 + l15;
                atomicAdd(&Earr[j], cE[cc]);
                atomicAdd(&Sarr[j], cS[cc]);
                atomicAdd(&Carr[j], cC[cc]);
            }
        }
    }
}

// ---------------- flush row accumulators for the current I-block ----------------
__device__ __forceinline__ void flush_rows(int ibase, int wave, int quad, int l15,
                                           float (&rowE)[8], float (&rowS)[8], float (&rowC)[8],
                                           float* __restrict__ Earr,
                                           float* __restrict__ Sarr,
                                           float* __restrict__ Carr) {
#pragma unroll
    for (int idx = 0; idx < 8; ++idx) {
#pragma unroll
        for (int m = 1; m < 16; m <<= 1) {
            rowE[idx] += __shfl_xor(rowE[idx], m, 64);
            rowS[idx] += __shfl_xor(rowS[idx], m, 64);
            rowC[idx] += __shfl_xor(rowC[idx], m, 64);
        }
    }
    if (l15 == 0) {
#pragma unroll
        for (int idx = 0; idx < 8; ++idx) {
            int i = ibase + wave * 32 + (idx >> 2) * 16 + quad * 4 + (idx & 3);
            atomicAdd(&Earr[i], rowE[idx]);
            atomicAdd(&Sarr[i], rowS[idx]);
            atomicAdd(&Carr[i], rowC[idx]);
        }
    }
#pragma unroll
    for (int idx = 0; idx < 8; ++idx) { rowE[idx] = 0.f; rowS[idx] = 0.f; rowC[idx] = 0.f; }
}

// ---------------- triangular decode: g -> (I,J), J<=I ----------------
__device__ __forceinline__ void decodeIJ(int g, int& I, int& J) {
    int i = (int)((sqrtf(8.f * (float)g + 1.f) - 1.f) * 0.5f);
    while ((i + 1) * (i + 2) / 2 <= g) ++i;
    while (i * (i + 1) / 2 > g) --i;
    I = i; J = g - i * (i + 1) / 2;
}

// ---------------- round-6 body, CNT consecutive pairs, statically unrolled -------
template<int CNT>
__device__ __forceinline__ void run_pairs(int g0, const ushortT* __restrict__ hn,
                                          const float4* __restrict__ p4,
                                          float* __restrict__ Earr,
                                          float* __restrict__ Sarr,
                                          float* __restrict__ Carr,
                                          ushortT (&Bs)[2][128 * D],
                                          int wave, int lane, int quad, int l15) {
    int Iarr[CNT], Jarr[CNT];
    {
        int I, J;
        decodeIJ(g0, I, J);
#pragma unroll
        for (int p = 0; p < CNT; ++p) {
            Iarr[p] = I; Jarr[p] = J;
            if (++J > I) { ++I; J = 0; }
        }
    }

    stage128_swz(hn + (size_t)Jarr[0] * 128 * D, Bs[0], wave, lane);
    stage128_swz(hn + (size_t)Jarr[1] * 128 * D, Bs[1], wave, lane);

    short8 afr[4][2];
    loadA(hn, Iarr[0] * 128, wave, quad, l15, afr);

    float rowE[8], rowS[8], rowC[8];
#pragma unroll
    for (int idx = 0; idx < 8; ++idx) { rowE[idx] = 0.f; rowS[idx] = 0.f; rowC[idx] = 0.f; }

    __syncthreads();   // drains Bs[0]+Bs[1] staging (+afr loads)

#pragma unroll
    for (int p = 0; p < CNT; ++p) {
        const int ib = Iarr[p] * 128, jb = Jarr[p] * 128;
        const bool diag = (Iarr[p] == Jarr[p]);
        if (p && Iarr[p] != Iarr[p - 1]) {       // block-uniform, rare
            flush_rows(Iarr[p - 1] * 128, wave, quad, l15, rowE, rowS, rowC, Earr, Sarr, Carr);
            loadA(hn, ib, wave, quad, l15, afr);
        }
        const ushortT* Bcur = Bs[p & 1];

        f32x4 acc[2][4];
        mfma_half(Bcur, afr, 0, quad, l15, acc);
        if (diag) epi_half<true >(acc, 0, ib, jb, wave, quad, l15, p4, rowE, rowS, rowC, Earr, Sarr, Carr);
        else      epi_half<false>(acc, 0, ib, jb, wave, quad, l15, p4, rowE, rowS, rowC, Earr, Sarr, Carr);

        mfma_half(Bcur, afr, 4, quad, l15, acc);
        // all Bcur reads done; barrier also drains the in-flight staging of pair p+1
        __syncthreads();
        if (p + 2 < CNT)
            stage128_swz(hn + (size_t)Jarr[p + 2] * 128 * D, Bs[p & 1], wave, lane);

        if (diag) epi_half<true >(acc, 4, ib, jb, wave, quad, l15, p4, rowE, rowS, rowC, Earr, Sarr, Carr);
        else      epi_half<false>(acc, 4, ib, jb, wave, quad, l15, p4, rowE, rowS, rowC, Earr, Sarr, Carr);
    }

    flush_rows(Iarr[CNT - 1] * 128, wave, quad, l15, rowE, rowS, rowC, Earr, Sarr, Carr);
}

// ---------------- fused MFMA sim + softmax partials, balanced static grid --------
// Session optimum (round 10, measured 43.4us main / 101.1us total). Symmetric
// triangular decomposition (half the MFMA/epilogue work), XOR-swizzled
// global_load_lds staging, double-buffered LDS, 2080 pairs balanced over exactly
// 512 blocks (2/CU, no straggler round: blocks 0..31 take 5 pairs, rest take 4).
// Fusion experiments (r11-r16: cooperative grid.sync, in-kernel atomic tail)
// all regressed or failed; 3-kernel structure is the empirical optimum here.
__global__ __launch_bounds__(256, 2) void main_kernel(const ushortT* __restrict__ hn,
                                                      const float4* __restrict__ p4,
                                                      float* __restrict__ Earr,
                                                      float* __restrict__ Sarr,
                                                      float* __restrict__ Carr) {
    __shared__ ushortT Bs[2][128 * D];   // 64 KB double buffer
    const int tid = threadIdx.x;
    const int wave = tid >> 6, lane = tid & 63;
    const int quad = lane >> 4, l15 = lane & 15;
    const int b = (int)blockIdx.x;

    if (b < XTRA)
        run_pairs<5>(b * 5, hn, p4, Earr, Sarr, Carr, Bs, wave, lane, quad, l15);
    else
        run_pairs<4>(XTRA * 5 + (b - XTRA) * 4, hn, p4, Earr, Sarr, Carr, Bs, wave, lane, quad, l15);
}

// ---------------- finalize (single kernel, atomic tail) ----------------
__global__ __launch_bounds__(256) void finalize_kernel(const float* __restrict__ Earr,
                                                       const float* __restrict__ Sarr,
                                                       const float* __restrict__ Carr,
                                                       float* __restrict__ tailf,
                                                       float* __restrict__ out) {
    const int tid = threadIdx.x;
    const int a = blockIdx.x * 256 + tid;
    float E = Earr[a], S = Sarr[a], C = Carr[a];
    float L = 0.f, V = 0.f;
    if (C > 0.f) {
        float lse = 10.0f + logf(E);
        L = -(10.0f * S - C * lse) / C;   // S stored in sim units
        V = 1.0f;
    }
#pragma unroll
    for (int m = 1; m < 64; m <<= 1) {
        L += __shfl_xor(L, m, 64);
        V += __shfl_xor(V, m, 64);
    }
    __shared__ float sL[4], sV[4];
    __shared__ int isLast;
    const int wave = tid >> 6, lane = tid & 63;
    if (lane == 0) { sL[wave] = L; sV[wave] = V; }
    __syncthreads();
    if (tid == 0) {
        float Lb = sL[0] + sL[1] + sL[2] + sL[3];
        float Vb = sV[0] + sV[1] + sV[2] + sV[3];
        atomicExch(&tailf[1 + blockIdx.x], Lb);        // coherent-point publish
        atomicExch(&tailf[33 + blockIdx.x], Vb);
        __threadfence();
        unsigned old = atomicAdd((unsigned*)tailf, 1u);
        isLast = (old == 31) ? 1 : 0;
    }
    __syncthreads();
    if (isLast && tid < 64) {
        __threadfence();
        float Lv = (tid < 32) ? atomicAdd(&tailf[1 + tid], 0.0f) : 0.f;    // coherent read
        float Vv = (tid < 32) ? atomicAdd(&tailf[33 + tid], 0.0f) : 0.f;
#pragma unroll
        for (int m = 1; m < 32; m <<= 1) {   // fixed-order tree: deterministic
            Lv += __shfl_xor(Lv, m, 64);
            Vv += __shfl_xor(Vv, m, 64);
        }
        if (tid == 0) out[0] = Lv / fmaxf(Vv, 1.0f);
    }
}

extern "C" void kernel_launch(void* const* d_in, const int* in_sizes, int n_in,
                              void* d_out, int out_size, void* d_ws, size_t ws_size,
                              hipStream_t stream) {
    const float* h = (const float*)d_in[0];     // [8,1024,128] fp32
    const float* pos = (const float*)d_in[1];   // [8,1024,3] fp32
    float* out = (float*)d_out;                 // scalar fp32

    char* ws = (char*)d_ws;
    ushortT* hn = (ushortT*)ws;                                   // 8192*128*2 = 2 MB bf16
    float4* p4 = (float4*)(ws + (size_t)N_TOT * D * 2);           // 128 KB
    char* p = ws + (size_t)N_TOT * D * 2 + (size_t)N_TOT * 16;
    float* Earr = (float*)p; p += (size_t)N_TOT * 4;              // 32 KB
    float* Sarr = (float*)p; p += (size_t)N_TOT * 4;              // 32 KB
    float* Carr = (float*)p; p += (size_t)N_TOT * 4;              // 32 KB
    float* tailf = (float*)p;   // [0]=finalize cnt, [1..33)=L, [33..65)=V

    prep_kernel<<<N_TOT / 4, 256, 0, stream>>>(h, pos, (unsigned*)hn, p4,
                                               Earr, Sarr, Carr, (unsigned*)tailf);
    main_kernel<<<NBLK, 256, 0, stream>>>(hn, p4, Earr, Sarr, Carr);
    finalize_kernel<<<N_TOT / 256, 256, 0, stream>>>(Earr, Sarr, Carr, tailf, out);
}